// Round 1
// baseline (243.015 us; speedup 1.0000x reference)
//
#include <hip/hip_runtime.h>
#include <hip/hip_bf16.h>
#include <stdint.h>

typedef __attribute__((ext_vector_type(8))) short bf16x8;
typedef __attribute__((ext_vector_type(4))) float f32x4;

__device__ __forceinline__ float bf2f(unsigned short u) {
    union { unsigned int i; float f; } z; z.i = ((unsigned int)u) << 16; return z.f;
}
__device__ __forceinline__ unsigned short f2bf(float f) {
    union { float f; unsigned int i; } z; z.f = f;
    unsigned int x = z.i;
    unsigned int r = x + 0x7fffu + ((x >> 16) & 1u);
    return (unsigned short)(r >> 16);
}

typedef const __attribute__((address_space(1))) unsigned int* gp_t;
typedef __attribute__((address_space(3))) unsigned int* lp_t;

__device__ __forceinline__ void gload_lds16(const void* g, void* l) {
    __builtin_amdgcn_global_load_lds((gp_t)g, (lp_t)l, 16, 0, 0);
}

// ---------------- fp32 -> bf16 conversion (optionally scaled) ----------------
__global__ __launch_bounds__(256) void cvt_kernel(const float* __restrict__ in,
                                                  unsigned short* __restrict__ out,
                                                  int n4, float scale) {
    int i = blockIdx.x * 256 + threadIdx.x;
    int stride = gridDim.x * 256;
    for (; i < n4; i += stride) {
        float4 v = reinterpret_cast<const float4*>(in)[i];
        ushort4 u;
        u.x = f2bf(v.x * scale);
        u.y = f2bf(v.y * scale);
        u.z = f2bf(v.z * scale);
        u.w = f2bf(v.w * scale);
        reinterpret_cast<ushort4*>(out)[i] = u;
    }
}

// ---------------- NT GEMM: C[M][N] = A[M][K] * B[N][K]^T ----------------
// MODE 0: bf16 output
// MODE 1: bf16 output, causal tile skip (skip blocks with nt > mt)
// MODE 2: fp32 output, causal K-limit (Keff = min(K, (mt+1)*128))
// 128x128 tile, BK=32, 256 threads (4 waves, 2x2), 4x4 16x16x32 frags/wave.
template<int MODE>
__global__ __launch_bounds__(256) void gemm_nt(
    const unsigned short* __restrict__ A, int lda, long long sA,
    const unsigned short* __restrict__ B, int ldb, long long sB,
    void* __restrict__ Cv, int ldc, long long sC, int K)
{
    const int mt = blockIdx.x, nt = blockIdx.y, z = blockIdx.z;
    if (MODE == 1 && nt > mt) return;
    const unsigned short* Ab = A + (size_t)z * sA;
    const unsigned short* Bb = B + (size_t)z * sB;
    const int Keff = (MODE == 2) ? (((mt + 1) * 128 < K) ? (mt + 1) * 128 : K) : K;

    __shared__ unsigned short As[128 * 32];
    __shared__ unsigned short Bs[128 * 32];

    const int tid = threadIdx.x;
    const int l = tid & 63, w = tid >> 6;
    const int wr = w >> 1, wc = w & 1;
    const int m0 = mt * 128, n0 = nt * 128;
    const int lrow = l & 15, lsub = l >> 4;

    f32x4 acc[4][4] = {};

    for (int k0 = 0; k0 < Keff; k0 += 32) {
        // stage A,B tiles (128x32 bf16 each) via global_load_lds width=16
        #pragma unroll
        for (int j = 0; j < 2; ++j) {
            const int cc = (j * 4 + w) * 64 + l;   // 16B chunk id, 0..511
            const int row = cc >> 2, sub = cc & 3;
            gload_lds16(Ab + (size_t)(m0 + row) * lda + k0 + sub * 8,
                        (char*)As + (size_t)(j * 4 + w) * 1024);
            gload_lds16(Bb + (size_t)(n0 + row) * ldb + k0 + sub * 8,
                        (char*)Bs + (size_t)(j * 4 + w) * 1024);
        }
        __syncthreads();

        bf16x8 af[4], bfr[4];
        #pragma unroll
        for (int m = 0; m < 4; ++m)
            af[m] = *reinterpret_cast<const bf16x8*>(&As[(wr * 64 + m * 16 + lrow) * 32 + lsub * 8]);
        #pragma unroll
        for (int n = 0; n < 4; ++n)
            bfr[n] = *reinterpret_cast<const bf16x8*>(&Bs[(wc * 64 + n * 16 + lrow) * 32 + lsub * 8]);

        #pragma unroll
        for (int m = 0; m < 4; ++m)
            #pragma unroll
            for (int n = 0; n < 4; ++n)
                acc[m][n] = __builtin_amdgcn_mfma_f32_16x16x32_bf16(af[m], bfr[n], acc[m][n], 0, 0, 0);

        __syncthreads();
    }

    // epilogue: C/D layout col = lane&15, row = (lane>>4)*4 + reg
    const int crow = (l >> 4) * 4, ccol = l & 15;
    if (MODE == 2) {
        float* C = (float*)Cv + (size_t)z * sC;
        #pragma unroll
        for (int m = 0; m < 4; ++m)
            #pragma unroll
            for (int n = 0; n < 4; ++n) {
                const size_t rbase = (size_t)(m0 + wr * 64 + m * 16 + crow);
                const size_t cg = (size_t)(n0 + wc * 64 + n * 16 + ccol);
                #pragma unroll
                for (int r = 0; r < 4; ++r)
                    C[(rbase + r) * ldc + cg] = acc[m][n][r];
            }
    } else {
        unsigned short* C = (unsigned short*)Cv + (size_t)z * sC;
        #pragma unroll
        for (int m = 0; m < 4; ++m)
            #pragma unroll
            for (int n = 0; n < 4; ++n) {
                const size_t rbase = (size_t)(m0 + wr * 64 + m * 16 + crow);
                const size_t cg = (size_t)(n0 + wc * 64 + n * 16 + ccol);
                #pragma unroll
                for (int r = 0; r < 4; ++r)
                    C[(rbase + r) * ldc + cg] = f2bf(acc[m][n][r]);
            }
    }
}

// ---------------- causal row softmax, in-place on bf16 scores ----------------
// one 256-thread block per row; 8 elements per thread held in registers
__global__ __launch_bounds__(256) void softmax_causal(unsigned short* __restrict__ P) {
    const int S = 2048;
    const int gq = blockIdx.x;
    const int q = gq & (S - 1);
    unsigned short* row = P + (size_t)gq * S;
    const int t = threadIdx.x;
    const int c0 = t * 8;
    const int l = t & 63, w = t >> 6;
    const float NEG = -__builtin_huge_valf();

    uint4 rv = *reinterpret_cast<const uint4*>(row + c0);
    unsigned short us[8];
    us[0] = rv.x & 0xffff; us[1] = rv.x >> 16;
    us[2] = rv.y & 0xffff; us[3] = rv.y >> 16;
    us[4] = rv.z & 0xffff; us[5] = rv.z >> 16;
    us[6] = rv.w & 0xffff; us[7] = rv.w >> 16;

    float f[8];
    #pragma unroll
    for (int i = 0; i < 8; ++i)
        f[i] = (c0 + i <= q) ? bf2f(us[i]) : NEG;

    float m = f[0];
    #pragma unroll
    for (int i = 1; i < 8; ++i) m = fmaxf(m, f[i]);
    #pragma unroll
    for (int o = 1; o < 64; o <<= 1) m = fmaxf(m, __shfl_xor(m, o));

    __shared__ float smax[4], ssum[4];
    if (l == 0) smax[w] = m;
    __syncthreads();
    m = fmaxf(fmaxf(smax[0], smax[1]), fmaxf(smax[2], smax[3]));

    float e[8];
    float s = 0.f;
    #pragma unroll
    for (int i = 0; i < 8; ++i) {
        e[i] = exp2f((f[i] - m) * 1.44269504f);   // exp(x-m); -inf -> 0
        s += e[i];
    }
    #pragma unroll
    for (int o = 1; o < 64; o <<= 1) s += __shfl_xor(s, o);
    if (l == 0) ssum[w] = s;
    __syncthreads();
    s = ssum[0] + ssum[1] + ssum[2] + ssum[3];
    const float inv = 1.0f / s;

    uint4 ov;
    unsigned int p01 = f2bf(e[0] * inv) | ((unsigned int)f2bf(e[1] * inv) << 16);
    unsigned int p23 = f2bf(e[2] * inv) | ((unsigned int)f2bf(e[3] * inv) << 16);
    unsigned int p45 = f2bf(e[4] * inv) | ((unsigned int)f2bf(e[5] * inv) << 16);
    unsigned int p67 = f2bf(e[6] * inv) | ((unsigned int)f2bf(e[7] * inv) << 16);
    ov.x = p01; ov.y = p23; ov.z = p45; ov.w = p67;
    *reinterpret_cast<uint4*>(row + c0) = ov;
}

extern "C" void kernel_launch(void* const* d_in, const int* in_sizes, int n_in,
                              void* d_out, int out_size, void* d_ws, size_t ws_size,
                              hipStream_t stream) {
    const float* x  = (const float*)d_in[0];
    const float* Wq = (const float*)d_in[1];
    const float* Wk = (const float*)d_in[2];
    const float* Wv = (const float*)d_in[3];
    float* out = (float*)d_out;

    const int Bz = 4, S = 2048, D = 1024;
    const int MS = Bz * S; // 8192

    char* ws = (char*)d_ws;
    unsigned short* xb  = (unsigned short*)(ws);                         // 16 MB [8192][1024]
    unsigned short* wqb = (unsigned short*)(ws + (16ull << 20));         //  2 MB (pre-scaled by 1/32)
    unsigned short* wkb = (unsigned short*)(ws + (18ull << 20));         //  2 MB
    unsigned short* wvb = (unsigned short*)(ws + (20ull << 20));         //  2 MB
    unsigned short* qb  = (unsigned short*)(ws + (22ull << 20));         // 16 MB [8192][1024]
    unsigned short* kb  = (unsigned short*)(ws + (38ull << 20));         // 16 MB
    unsigned short* vt  = (unsigned short*)(ws + (54ull << 20));         // 16 MB [1024][8192] (V^T)
    unsigned short* sc  = (unsigned short*)(ws + (70ull << 20));         // 32 MB [4][2048][2048]

    // 1. bf16 conversion; fold softmax scale 1/sqrt(D)=1/32 into Wq
    cvt_kernel<<<2048, 256, 0, stream>>>(x,  xb,  MS * D / 4, 1.0f);
    cvt_kernel<<<512,  256, 0, stream>>>(Wq, wqb, D * D / 4, 0.03125f);
    cvt_kernel<<<512,  256, 0, stream>>>(Wk, wkb, D * D / 4, 1.0f);
    cvt_kernel<<<512,  256, 0, stream>>>(Wv, wvb, D * D / 4, 1.0f);

    // 2. projections: Q = xb*Wq^T, K = xb*Wk^T, Vt = Wv*xb^T  (all NT form)
    gemm_nt<0><<<dim3(MS / 128, D / 128, 1), 256, 0, stream>>>(xb, D, 0, wqb, D, 0, qb, D, 0, D);
    gemm_nt<0><<<dim3(MS / 128, D / 128, 1), 256, 0, stream>>>(xb, D, 0, wkb, D, 0, kb, D, 0, D);
    gemm_nt<0><<<dim3(D / 128, MS / 128, 1), 256, 0, stream>>>(wvb, D, 0, xb, D, 0, vt, MS, 0, D);

    // 3. scores = Q * K^T per batch (bf16 out), skip strictly-upper tiles
    gemm_nt<1><<<dim3(S / 128, S / 128, Bz), 256, 0, stream>>>(
        qb, D, (long long)S * D, kb, D, (long long)S * D, sc, S, (long long)S * S, D);

    // 4. causal softmax in place (writes zeros above diagonal)
    softmax_causal<<<MS, 256, 0, stream>>>(sc);

    // 5. out = P * V  ==  P * Vt^T  (NT, fp32 out, causal K-limit)
    gemm_nt<2><<<dim3(S / 128, D / 128, Bz), 256, 0, stream>>>(
        sc, S, (long long)S * S, vt, MS, S, out, D, (long long)S * D, S);
}

// Round 2
// 194.990 us; speedup vs baseline: 1.2463x; 1.2463x over previous
//
#include <hip/hip_runtime.h>
#include <hip/hip_bf16.h>
#include <stdint.h>

typedef __attribute__((ext_vector_type(8))) short bf16x8;
typedef __attribute__((ext_vector_type(4))) float f32x4;

__device__ __forceinline__ float bf2f(unsigned short u) {
    union { unsigned int i; float f; } z; z.i = ((unsigned int)u) << 16; return z.f;
}
__device__ __forceinline__ unsigned short f2bf(float f) {
    union { float f; unsigned int i; } z; z.f = f;
    unsigned int x = z.i;
    unsigned int r = x + 0x7fffu + ((x >> 16) & 1u);
    return (unsigned short)(r >> 16);
}

typedef const __attribute__((address_space(1))) unsigned int* gp_t;
typedef __attribute__((address_space(3))) unsigned int* lp_t;

__device__ __forceinline__ void gload_lds16(const void* g, void* l) {
    __builtin_amdgcn_global_load_lds((gp_t)g, (lp_t)l, 16, 0, 0);
}

// bijective XCD-aware remap (m204 form), decompose with mt fastest
__device__ __forceinline__ void xcd_swizzle(int& mt, int& nt, int& z) {
    const int GX = gridDim.x, GY = gridDim.y;
    const int nwg = GX * GY * gridDim.z;
    const int orig = blockIdx.x + GX * (blockIdx.y + GY * blockIdx.z);
    const int q = nwg >> 3, r = nwg & 7;
    const int xcd = orig & 7, pos = orig >> 3;
    const int wgid = (xcd < r ? xcd * (q + 1) : r * (q + 1) + (xcd - r) * q) + pos;
    mt = wgid % GX;
    const int t = wgid / GX;
    nt = t % GY;
    z = t / GY;
}

// ---------------- fp32 -> bf16 conversion (optionally scaled) ----------------
__global__ __launch_bounds__(256) void cvt_kernel(const float* __restrict__ in,
                                                  unsigned short* __restrict__ out,
                                                  int n4, float scale) {
    int i = blockIdx.x * 256 + threadIdx.x;
    int stride = gridDim.x * 256;
    for (; i < n4; i += stride) {
        float4 v = reinterpret_cast<const float4*>(in)[i];
        ushort4 u;
        u.x = f2bf(v.x * scale);
        u.y = f2bf(v.y * scale);
        u.z = f2bf(v.z * scale);
        u.w = f2bf(v.w * scale);
        reinterpret_cast<ushort4*>(out)[i] = u;
    }
}

// ---------------- NT GEMM: C[M][N] = A[M][K] * B[N][K]^T ----------------
// MODE 1: bf16 output, causal tile skip (skip blocks with nt > mt)
// MODE 2: fp32 output, causal K-limit (Keff = min(K, (mt+1)*128))
// MODE 3: fused QKV epilogue: nt<8 -> Q (bf16, C0), nt<16 -> K (bf16, C1),
//         nt>=16 -> V written TRANSPOSED into C2 = Vt[1024][8192]
// 128x128 tile, BK=32, 256 threads (4 waves, 2x2), 4x4 16x16x32 frags/wave.
// 2-phase double-buffered global_load_lds staging, 1 barrier per K-step.
template<int MODE>
__global__ __launch_bounds__(256) void gemm_nt(
    const unsigned short* __restrict__ A, int lda, long long sA,
    const unsigned short* __restrict__ B, int ldb, long long sB,
    void* __restrict__ C0, void* __restrict__ C1, void* __restrict__ C2,
    int ldc, long long sC, int K)
{
    int mt, nt, z;
    xcd_swizzle(mt, nt, z);
    if (MODE == 1 && nt > mt) return;
    const unsigned short* Ab = A + (size_t)z * sA;
    const unsigned short* Bb = B + (size_t)z * sB;
    const int Keff = (MODE == 2) ? (((mt + 1) * 128 < K) ? (mt + 1) * 128 : K) : K;
    const int nk = Keff >> 5;

    __shared__ unsigned short As[2][128 * 32];
    __shared__ unsigned short Bs[2][128 * 32];

    const int tid = threadIdx.x;
    const int l = tid & 63, w = tid >> 6;
    const int wr = w >> 1, wc = w & 1;
    const int m0 = mt * 128, n0 = nt * 128;
    const int lrow = l & 15, lsub = l >> 4;

    f32x4 acc[4][4] = {};

    auto stage = [&](int t, int b) {
        const int k0 = t * 32;
        #pragma unroll
        for (int j = 0; j < 2; ++j) {
            const int cc = (j * 4 + w) * 64 + l;   // 16B chunk id, 0..511
            const int row = cc >> 2, sub = cc & 3;
            gload_lds16(Ab + (size_t)(m0 + row) * lda + k0 + sub * 8,
                        (char*)&As[b][0] + (size_t)(j * 4 + w) * 1024);
            gload_lds16(Bb + (size_t)(n0 + row) * ldb + k0 + sub * 8,
                        (char*)&Bs[b][0] + (size_t)(j * 4 + w) * 1024);
        }
    };

    stage(0, 0);
    __syncthreads();
    int buf = 0;
    for (int t = 0; t < nk; ++t) {
        if (t + 1 < nk) stage(t + 1, buf ^ 1);   // prefetch next tile, other buffer

        bf16x8 af[4], bfr[4];
        #pragma unroll
        for (int m = 0; m < 4; ++m)
            af[m] = *reinterpret_cast<const bf16x8*>(&As[buf][(wr * 64 + m * 16 + lrow) * 32 + lsub * 8]);
        #pragma unroll
        for (int n = 0; n < 4; ++n)
            bfr[n] = *reinterpret_cast<const bf16x8*>(&Bs[buf][(wc * 64 + n * 16 + lrow) * 32 + lsub * 8]);

        #pragma unroll
        for (int m = 0; m < 4; ++m)
            #pragma unroll
            for (int n = 0; n < 4; ++n)
                acc[m][n] = __builtin_amdgcn_mfma_f32_16x16x32_bf16(af[m], bfr[n], acc[m][n], 0, 0, 0);

        __syncthreads();   // implicit vmcnt(0)+lgkmcnt(0) drain covers the prefetch
        buf ^= 1;
    }

    // epilogue: C/D layout col = lane&15, row = (lane>>4)*4 + reg
    const int crow = (l >> 4) * 4, ccol = l & 15;
    if (MODE == 2) {
        float* C = (float*)C0 + (size_t)z * sC;
        #pragma unroll
        for (int m = 0; m < 4; ++m)
            #pragma unroll
            for (int n = 0; n < 4; ++n) {
                const size_t rbase = (size_t)(m0 + wr * 64 + m * 16 + crow);
                const size_t cg = (size_t)(n0 + wc * 64 + n * 16 + ccol);
                #pragma unroll
                for (int r = 0; r < 4; ++r)
                    C[(rbase + r) * ldc + cg] = acc[m][n][r];
            }
    } else if (MODE == 1) {
        unsigned short* C = (unsigned short*)C0 + (size_t)z * sC;
        #pragma unroll
        for (int m = 0; m < 4; ++m)
            #pragma unroll
            for (int n = 0; n < 4; ++n) {
                const size_t rbase = (size_t)(m0 + wr * 64 + m * 16 + crow);
                const size_t cg = (size_t)(n0 + wc * 64 + n * 16 + ccol);
                #pragma unroll
                for (int r = 0; r < 4; ++r)
                    C[(rbase + r) * ldc + cg] = f2bf(acc[m][n][r]);
            }
    } else { // MODE 3: fused QKV
        if (nt < 16) {
            unsigned short* C = (unsigned short*)(nt < 8 ? C0 : C1);
            const int cb = (nt < 8) ? n0 : n0 - 1024;
            #pragma unroll
            for (int m = 0; m < 4; ++m)
                #pragma unroll
                for (int n = 0; n < 4; ++n) {
                    const size_t rbase = (size_t)(m0 + wr * 64 + m * 16 + crow);
                    const size_t cg = (size_t)(cb + wc * 64 + n * 16 + ccol);
                    #pragma unroll
                    for (int r = 0; r < 4; ++r)
                        C[(rbase + r) * ldc + cg] = f2bf(acc[m][n][r]);
                }
        } else {
            unsigned short* Vt = (unsigned short*)C2;   // [1024][8192]
            #pragma unroll
            for (int m = 0; m < 4; ++m)
                #pragma unroll
                for (int n = 0; n < 4; ++n) {
                    const int rbase = m0 + wr * 64 + m * 16 + crow;
                    const int o = (n0 - 2048) + wc * 64 + n * 16 + ccol;
                    ushort4 u;
                    u.x = f2bf(acc[m][n][0]);
                    u.y = f2bf(acc[m][n][1]);
                    u.z = f2bf(acc[m][n][2]);
                    u.w = f2bf(acc[m][n][3]);
                    *reinterpret_cast<ushort4*>(&Vt[(size_t)o * 8192 + rbase]) = u;
                }
        }
    }
}

// ---------------- causal row softmax, in-place on bf16 scores ----------------
// one 256-thread block per row; reads cols <= q, writes cols < ((q>>7)+1)*128
// (exactly the extent the PV GEMM's causal K-limit will read; rest never touched)
__global__ __launch_bounds__(256) void softmax_causal(unsigned short* __restrict__ P) {
    const int S = 2048;
    const int gq = blockIdx.x;
    const int q = gq & (S - 1);
    unsigned short* row = P + (size_t)gq * S;
    const int t = threadIdx.x;
    const int c0 = t * 8;
    const int l = t & 63, w = t >> 6;
    const int wlim = ((q >> 7) + 1) << 7;
    const float NEG = -__builtin_huge_valf();

    float f[8];
    if (c0 <= q) {
        uint4 rv = *reinterpret_cast<const uint4*>(row + c0);
        unsigned short us[8];
        us[0] = rv.x & 0xffff; us[1] = rv.x >> 16;
        us[2] = rv.y & 0xffff; us[3] = rv.y >> 16;
        us[4] = rv.z & 0xffff; us[5] = rv.z >> 16;
        us[6] = rv.w & 0xffff; us[7] = rv.w >> 16;
        #pragma unroll
        for (int i = 0; i < 8; ++i)
            f[i] = (c0 + i <= q) ? bf2f(us[i]) : NEG;
    } else {
        #pragma unroll
        for (int i = 0; i < 8; ++i) f[i] = NEG;
    }

    float m = f[0];
    #pragma unroll
    for (int i = 1; i < 8; ++i) m = fmaxf(m, f[i]);
    #pragma unroll
    for (int o = 1; o < 64; o <<= 1) m = fmaxf(m, __shfl_xor(m, o));

    __shared__ float smax[4], ssum[4];
    if (l == 0) smax[w] = m;
    __syncthreads();
    m = fmaxf(fmaxf(smax[0], smax[1]), fmaxf(smax[2], smax[3]));

    float e[8];
    float s = 0.f;
    #pragma unroll
    for (int i = 0; i < 8; ++i) {
        e[i] = exp2f((f[i] - m) * 1.44269504f);   // exp(x-m); -inf -> 0
        s += e[i];
    }
    #pragma unroll
    for (int o = 1; o < 64; o <<= 1) s += __shfl_xor(s, o);
    if (l == 0) ssum[w] = s;
    __syncthreads();
    s = ssum[0] + ssum[1] + ssum[2] + ssum[3];
    const float inv = 1.0f / s;

    if (c0 < wlim) {
        uint4 ov;
        ov.x = f2bf(e[0] * inv) | ((unsigned int)f2bf(e[1] * inv) << 16);
        ov.y = f2bf(e[2] * inv) | ((unsigned int)f2bf(e[3] * inv) << 16);
        ov.z = f2bf(e[4] * inv) | ((unsigned int)f2bf(e[5] * inv) << 16);
        ov.w = f2bf(e[6] * inv) | ((unsigned int)f2bf(e[7] * inv) << 16);
        *reinterpret_cast<uint4*>(row + c0) = ov;
    }
}

extern "C" void kernel_launch(void* const* d_in, const int* in_sizes, int n_in,
                              void* d_out, int out_size, void* d_ws, size_t ws_size,
                              hipStream_t stream) {
    const float* x  = (const float*)d_in[0];
    const float* Wq = (const float*)d_in[1];
    const float* Wk = (const float*)d_in[2];
    const float* Wv = (const float*)d_in[3];
    float* out = (float*)d_out;

    const int Bz = 4, S = 2048, D = 1024;
    const int MS = Bz * S;       // 8192
    const int DD = D * D;

    char* ws = (char*)d_ws;
    unsigned short* xb   = (unsigned short*)(ws);                      // 16 MB [8192][1024]
    unsigned short* wqkv = (unsigned short*)(ws + (16ull << 20));      //  6 MB [3072][1024] (Wq pre-scaled 1/32)
    unsigned short* qb   = (unsigned short*)(ws + (22ull << 20));      // 16 MB [8192][1024]
    unsigned short* kb   = (unsigned short*)(ws + (38ull << 20));      // 16 MB [8192][1024]
    unsigned short* vt   = (unsigned short*)(ws + (54ull << 20));      // 16 MB [1024][8192] (V^T)
    unsigned short* sc   = (unsigned short*)(ws + (70ull << 20));      // 32 MB [4][2048][2048]

    // 1. bf16 conversion; fold softmax scale 1/sqrt(D)=1/32 into Wq
    cvt_kernel<<<2048, 256, 0, stream>>>(x,  xb, MS * D / 4, 1.0f);
    cvt_kernel<<<512,  256, 0, stream>>>(Wq, wqkv,          DD / 4, 0.03125f);
    cvt_kernel<<<512,  256, 0, stream>>>(Wk, wqkv + DD,     DD / 4, 1.0f);
    cvt_kernel<<<512,  256, 0, stream>>>(Wv, wqkv + 2 * DD, DD / 4, 1.0f);

    // 2. fused QKV projection: [8192][3072] = xb * Wqkv^T; V slice stored transposed
    gemm_nt<3><<<dim3(MS / 128, 24, 1), 256, 0, stream>>>(
        xb, D, 0, wqkv, D, 0, qb, kb, vt, D, 0, D);

    // 3. scores = Q * K^T per batch (bf16 out), skip strictly-upper tiles
    gemm_nt<1><<<dim3(S / 128, S / 128, Bz), 256, 0, stream>>>(
        qb, D, (long long)S * D, kb, D, (long long)S * D, sc, nullptr, nullptr,
        S, (long long)S * S, D);

    // 4. causal softmax in place (zero-fills up to the PV read extent)
    softmax_causal<<<MS, 256, 0, stream>>>(sc);

    // 5. out = P * V == P * Vt^T  (NT, fp32 out, causal K-limit)
    gemm_nt<2><<<dim3(S / 128, D / 128, Bz), 256, 0, stream>>>(
        sc, S, (long long)S * S, vt, MS, S, out, nullptr, nullptr,
        D, (long long)S * D, S);
}